// Round 5
// baseline (128.194 us; speedup 1.0000x reference)
//
#include <hip/hip_runtime.h>

// ACELoss3D round 15: R14 body bit-identical + fence-free hierarchical
// finalize replacing the single-address atomicAdd.
// R13 calibration: same-address f32 atomics serialize at the coherence point
// at ~8.7ns each (6144 -> +53us; 1024 -> ~9us tail in R14). Fix: spread the
// per-block scalar over 64 lines (16 deep each, ~140ns), then a 2-level
// completion-counter chain (16-deep cnt1[64], 64-deep cnt2) picks the LAST
// block to reduce the lines and store out[0]. Ordering is purely by data
// dependence on RETURNED atomic values (asm "v" keeps the value-add's result
// live -> s_waitcnt before the counter bump): no fences, no L2 maintenance
// (R12 lesson). Finalizer reads lines via relaxed agent-scope atomic loads.
// History: R10 two-kernel 119.7us (main ~30us + final ~5us + 2x41us harness
// ws-poison fills); R11 cooperative launch no-ops under graph capture;
// R12 agent-scope fences = 518us catastrophe; R13 atomic contention (85us
// main); R14 bc-loop fuse 125.5us (main ~39 = ~30 compute + ~9 atomic tail).

static constexpr int   NTOT   = 6 * 128 * 128 * 128;   // 12,582,912
static constexpr int   GRID   = 1024;                  // 32x32 xy-tiles
static constexpr float ALPHA_ = 0.001f;
static constexpr float MIU_   = 1.0f;
static constexpr float EPS_   = 1e-8f;

__device__ __forceinline__ void wave_reduce3(float& a, float& b, float& c) {
#pragma unroll
  for (int off = 32; off > 0; off >>= 1) {
    a += __shfl_down(a, off);
    b += __shfl_down(b, off);
    c += __shfl_down(c, off);
  }
}

// One output element. di/dj = un-halved first diffs; sx/sy = uxp+uxm, uyp+uym;
// dik/djk/dij = un-halved mixed double-diffs. 2*cik*cjk*cij = 0.25*dik*djk*dij.
__device__ __forceinline__ void elem(
    float uzm, float u0, float uzp,
    float di, float sx, float dj, float sy,
    float dik, float djk, float dij,
    float t, float& s1, float& s2, float& s3) {
  const float dk  = uzp - uzm;
  const float ci2 = 0.25f * di * di;
  const float cj2 = 0.25f * dj * dj;
  const float ck2 = 0.25f * dk * dk;
  const float u2  = u0 + u0;
  const float cii = sx - u2;
  const float cjj = sy - u2;
  const float ckk = (uzp + uzm) - u2;
  const float ss  = ci2 + cj2 + ck2;
  const float ss1 = 1.f + ss;
  const float L = (cii + cjj) + ckk;
  const float M = fmaf(ci2, cii, fmaf(cj2, cjj, ck2 * ckk));
  float curv = fmaf(ss1, L, -M);
  curv = fmaf(-0.25f * dij, dik * djk, curv);
  const float len = __builtin_amdgcn_sqrtf(EPS_ + ss);
  s3 = fmaf(curv * curv, len * __builtin_amdgcn_rcpf(ss1), s3);
  const float tm1 = t - 1.f;
  s1 = fmaf(u0, tm1 * tm1, s1);
  s2 = fmaf(1.f - u0, t * t, s2);
}

__global__ __launch_bounds__(512, 4) void ace_main(
    const float* __restrict__ pred, const float* __restrict__ truth,
    float* __restrict__ out, float* __restrict__ ws) {
  const int tid = threadIdx.x;
  // Block = one 4x4x128 xy-tile; thread -> (x-sub, y-sub, z-group).
  const int rem = blockIdx.x;               // 0..1023: 32x32 xy tiles
  const int x   = ((rem & 31) << 2)  + (tid >> 7);
  const int y   = ((rem >> 5) << 2)  + ((tid >> 5) & 3);
  const int z0  = (tid & 31) << 2;                         // 0,4,...,124

  // Wave halves: lanes 0-31 = even y-sub, lanes 32-63 = odd y-sub (adjacent y).
  const bool upper = (tid & 32) != 0;
  const float sgn  = upper ? 1.f : -1.f;
  const int yOut = upper ? ((y < 127) ? y + 1 : 127) : ((y > 0) ? y - 1 : 0);
  const int rO  = yOut << 7;
  const int rC  = y << 7;
  const int pC  = x << 14;
  const int pXp = ((x < 127) ? x + 1 : 127) << 14;
  const int pXm = ((x > 0)   ? x - 1 : 0)   << 14;
  // Loop-invariant element offsets (bc advances the base pointer only).
  const int iC  = pC  + rC + z0;
  const int iXP = pXp + rC + z0;
  const int iXM = pXm + rC + z0;
  const int iOY = pC  + rO + z0;
  const int iOP = pXp + rO + z0;
  const int iOM = pXm + rO + z0;
  const bool zlo = (z0 == 0), zhi = (z0 == 124);

  float s1 = 0.f, s2 = 0.f, s3 = 0.f;
  const float* __restrict__ bp = pred;
  const float* __restrict__ bt = truth;

#pragma unroll 1
  for (int bc = 0; bc < 6; ++bc) {
    // 7 float4 loads — all pinned in flight before any consumer.
    const float4 vC  = *(const float4*)(bp + iC);
    const float4 vXP = *(const float4*)(bp + iXP);
    const float4 vXM = *(const float4*)(bp + iXM);
    const float4 vOY = *(const float4*)(bp + iOY);   // outward y row
    const float4 vOP = *(const float4*)(bp + iOP);
    const float4 vOM = *(const float4*)(bp + iOM);
    const float4 t4  = *(const float4*)(bt + iC);
    bp += 1 << 21;
    bt += 1 << 21;
#if defined(__has_builtin)
#if __has_builtin(__builtin_amdgcn_sched_barrier)
    __builtin_amdgcn_sched_barrier(0);   // keep all 7 loads issued before math
#endif
#endif

    // Center-row x combines.
    const float dxa = vXP.x - vXM.x, dxb = vXP.y - vXM.y;
    const float dxc = vXP.z - vXM.z, dxd = vXP.w - vXM.w;
    const float sxa = vXP.x + vXM.x, sxb = vXP.y + vXM.y;
    const float sxc = vXP.z + vXM.z, sxd = vXP.w + vXM.w;
    // Outward-row x-diff.
    const float dOa = vOP.x - vOM.x, dOb = vOP.y - vOM.y;
    const float dOc = vOP.z - vOM.z, dOd = vOP.w - vOM.w;

    // Inward y-neighbor via half-wave exchange (partner row never clamped).
    const float iCa = __shfl_xor(vC.x, 32), iCb = __shfl_xor(vC.y, 32);
    const float iCc = __shfl_xor(vC.z, 32), iCd = __shfl_xor(vC.w, 32);
    const float iDa = __shfl_xor(dxa, 32),  iDb = __shfl_xor(dxb, 32);
    const float iDc = __shfl_xor(dxc, 32),  iDd = __shfl_xor(dxd, 32);

    // y combines: sy order-free; dy/j get the half sign.
    const float sya = iCa + vOY.x, syb = iCb + vOY.y;
    const float syc = iCc + vOY.z, syd = iCd + vOY.w;
    const float dya = sgn * (vOY.x - iCa), dyb = sgn * (vOY.y - iCb);
    const float dyc = sgn * (vOY.z - iCc), dyd = sgn * (vOY.w - iCd);
    const float ja  = sgn * (dOa - iDa),   jb  = sgn * (dOb - iDb);
    const float jc  = sgn * (dOc - iDc),   jd  = sgn * (dOd - iDd);

    // z-halo from adjacent lanes; clamp lanes select-overridden so the +-1
    // shuffles never leak across the 32-lane z-line boundary.
    float clo  = __shfl_up  (vC.w, 1);  clo  = zlo ? vC.x : clo;
    float chi  = __shfl_down(vC.x, 1);  chi  = zhi ? vC.w : chi;
    float dxm1 = __shfl_up  (dxd, 1);   dxm1 = zlo ? dxa : dxm1;
    float dxp4 = __shfl_down(dxa, 1);   dxp4 = zhi ? dxd : dxp4;
    float dym1 = __shfl_up  (dyd, 1);   dym1 = zlo ? dya : dym1;
    float dyp4 = __shfl_down(dya, 1);   dyp4 = zhi ? dyd : dyp4;

    elem(clo,  vC.x, vC.y, dxa, sxa, dya, sya, dxb - dxm1, dyb - dym1, ja, t4.x, s1, s2, s3);
    elem(vC.x, vC.y, vC.z, dxb, sxb, dyb, syb, dxc - dxa,  dyc - dya,  jb, t4.y, s1, s2, s3);
    elem(vC.y, vC.z, vC.w, dxc, sxc, dyc, syc, dxd - dxb,  dyd - dyb,  jc, t4.z, s1, s2, s3);
    elem(vC.z, vC.w, chi,  dxd, sxd, dyd, syd, dxp4 - dxc, dyp4 - dyc, jd, t4.w, s1, s2, s3);
  }

  // Block reduction -> one scalar v = MIU*s1 + s2 + s3.
  wave_reduce3(s1, s2, s3);
  __shared__ float l1[8], l2[8], l3[8];
  __shared__ int amFinal;
  const int lane = tid & 63, wv = tid >> 6;
  if (lane == 0) { l1[wv] = s1; l2[wv] = s2; l3[wv] = s3; }
  __syncthreads();

  float* __restrict__ lines = ws;                 // 64 f32 accumulator lines
  int*   __restrict__ cnt1  = (int*)(ws + 64);    // 64 group counters (16 deep)
  int*   __restrict__ cnt2  = (int*)(ws + 128);   // 1 super counter (64 deep)

  if (tid == 0) {
    float p1 = 0.f, p2 = 0.f, p3 = 0.f;
#pragma unroll
    for (int w = 0; w < 8; ++w) { p1 += l1[w]; p2 += l2[w]; p3 += l3[w]; }
    const float v = fmaf(MIU_, p1, p2 + p3);
    const int g = blockIdx.x & 63;
    // (a) value add, returning form; keep result live so the compiler emits
    // s_waitcnt before (b) -> the add is COMPLETE at the coherence point.
    float ov = atomicAdd(&lines[g], v);
    asm volatile("" :: "v"(ov));
    // (b) group counter; branch consumes the return -> ordered after (a).
    int last = 0;
    const int o1 = atomicAdd(&cnt1[g], 1);
    if (o1 == 15) {                 // 16th (last) block of this group
      const int o2 = atomicAdd(cnt2, 1);
      last = (o2 == 63);            // 64th (last) group -> all adds complete
    }
    amFinal = last;
  }
  __syncthreads();

  // Finalizer: reduce the 64 lines (coherence-point atomic loads, no fences)
  // and store the result. Nobody spins -> deadlock-free.
  if (amFinal && tid < 64) {
    float a = __hip_atomic_load(&lines[tid], __ATOMIC_RELAXED,
                                __HIP_MEMORY_SCOPE_AGENT);
#pragma unroll
    for (int off = 32; off > 0; off >>= 1) a += __shfl_down(a, off);
    if (tid == 0) out[0] = a + ALPHA_ * (float)NTOT;
  }
}

extern "C" void kernel_launch(void* const* d_in, const int* in_sizes, int n_in,
                              void* d_out, int out_size, void* d_ws, size_t ws_size,
                              hipStream_t stream) {
  const float* pred  = (const float*)d_in[0];   // y_pred
  const float* truth = (const float*)d_in[1];   // y_true
  float* out = (float*)d_out;
  float* ws  = (float*)d_ws;

  // Zero lines[64] + cnt1[64] + cnt2 in one tiny node (runs after the
  // harness's ws poison fill, stream-ordered).
  hipMemsetAsync(ws, 0, 516, stream);
  ace_main<<<GRID, 512, 0, stream>>>(pred, truth, out, ws);
}

// Round 6
// 117.231 us; speedup vs baseline: 1.0935x; 1.0935x over previous
//
#include <hip/hip_runtime.h>

// ACELoss3D round 16: champion R10 two-kernel skeleton + exact VALU cuts.
// R13-R15 post-mortem: all atomic-fusion variants (1 atomic, 64-line
// hierarchy) lost to R10's fire-and-forget partials + tiny final dispatch.
// Keep that structure. Main kernel is VALU-bound (R13: VALUBusy 26.5% x 85us
// => 22.5us absolute VALU time ~= 75% of the 30us R10 main; FETCH 61MB is
// only ~10us at BW roofline). Cuts, both algebraically exact:
//  (1) drop sgn mults: dj appears only as dj^2 and in dij*djk (sgn^2=1);
//      mult by +-1 is exact => bit-identical. -8 mul/thread/bc.
//  (2) region identity (MIU=1, abs no-op per R13 absmax 0.0):
//      u(t-1)^2+(1-u)t^2 = t*(t-2u)+u -> 3 ops/elem (was 6), and s1,s2,s3
//      collapse to ONE scalar/thread -> 1-value reduce, 1 partial/block.
// History: R10 119.7us champ; R11 coop launch no-ops under graph capture;
// R12 agent-scope fences 518us; R13 single-address atomics +55us; R14 bc-loop
// fuse 125.5; R15 counter-chain 128.2 (round-trip wait on critical path).

static constexpr int   NTOT   = 6 * 128 * 128 * 128;   // 12,582,912
static constexpr int   NBLK   = 6144;                  // 32x32 xy-tiles * 6 bc
static constexpr float ALPHA_ = 0.001f;
static constexpr float EPS_   = 1e-8f;

__device__ __forceinline__ void wave_reduce1(float& a) {
#pragma unroll
  for (int off = 32; off > 0; off >>= 1) a += __shfl_down(a, off);
}

// One output element. di/dj = un-halved first diffs (dj sign-free, see (1));
// sx/sy = uxp+uxm, uyp+uym; dik/djk/dij = un-halved mixed double-diffs.
// 2*cik*cjk*cij = 0.25*dik*djk*dij. Region: t*(t-2u)+u  (exact identity).
__device__ __forceinline__ void elem(
    float uzm, float u0, float uzp,
    float di, float sx, float dj, float sy,
    float dik, float djk, float dij,
    float t, float& s12, float& s3) {
  const float dk  = uzp - uzm;
  const float ci2 = 0.25f * di * di;
  const float cj2 = 0.25f * dj * dj;
  const float ck2 = 0.25f * dk * dk;
  const float u2  = u0 + u0;
  const float cii = sx - u2;
  const float cjj = sy - u2;
  const float ckk = (uzp + uzm) - u2;
  const float ss  = ci2 + cj2 + ck2;
  const float ss1 = 1.f + ss;
  const float L = (cii + cjj) + ckk;
  const float M = fmaf(ci2, cii, fmaf(cj2, cjj, ck2 * ckk));
  float curv = fmaf(ss1, L, -M);
  curv = fmaf(-0.25f * dij, dik * djk, curv);
  const float len = __builtin_amdgcn_sqrtf(EPS_ + ss);
  s3 = fmaf(curv * curv, len * __builtin_amdgcn_rcpf(ss1), s3);
  s12 += fmaf(t, fmaf(-2.f, u0, t), u0);    // u(t-1)^2+(1-u)t^2
}

__global__ __launch_bounds__(512, 4) void ace_main(
    const float* __restrict__ pred, const float* __restrict__ truth,
    float* __restrict__ partials) {
  const int tid = threadIdx.x;
  // Block -> (bc, y-tile, x-tile); thread -> (x-sub, y-sub, z-group).
  const int rem = blockIdx.x & 1023;        // 32x32 xy tiles
  const int bc  = blockIdx.x >> 10;         // 0..5
  const int x   = ((rem & 31) << 2)  + (tid >> 7);
  const int y   = ((rem >> 5) << 2)  + ((tid >> 5) & 3);
  const int z0  = (tid & 31) << 2;                         // 0,4,...,124
  const size_t base = ((size_t)bc) << 21;
  const float* __restrict__ bp = pred + base;

  // Wave halves: lanes 0-31 = even y-sub, lanes 32-63 = odd y-sub (adjacent y).
  const bool upper = (tid & 32) != 0;
  const int yOut = upper ? ((y < 127) ? y + 1 : 127) : ((y > 0) ? y - 1 : 0);
  const int rO  = yOut << 7;
  const int rC  = y << 7;
  const int pC  = x << 14;
  const int pXp = ((x < 127) ? x + 1 : 127) << 14;
  const int pXm = ((x > 0)   ? x - 1 : 0)   << 14;

  // 7 float4 loads — all pinned in flight before any consumer.
  const float4 vC  = *(const float4*)(bp + pC  + rC + z0);
  const float4 vXP = *(const float4*)(bp + pXp + rC + z0);
  const float4 vXM = *(const float4*)(bp + pXm + rC + z0);
  const float4 vOY = *(const float4*)(bp + pC  + rO + z0);   // outward y row
  const float4 vOP = *(const float4*)(bp + pXp + rO + z0);
  const float4 vOM = *(const float4*)(bp + pXm + rO + z0);
  const float4 t4  = *(const float4*)(truth + base + pC + rC + z0);
#if defined(__has_builtin)
#if __has_builtin(__builtin_amdgcn_sched_barrier)
  __builtin_amdgcn_sched_barrier(0);   // keep all 7 loads issued before math
#endif
#endif

  // Center-row x combines.
  const float dxa = vXP.x - vXM.x, dxb = vXP.y - vXM.y;
  const float dxc = vXP.z - vXM.z, dxd = vXP.w - vXM.w;
  const float sxa = vXP.x + vXM.x, sxb = vXP.y + vXM.y;
  const float sxc = vXP.z + vXM.z, sxd = vXP.w + vXM.w;
  // Outward-row x-diff.
  const float dOa = vOP.x - vOM.x, dOb = vOP.y - vOM.y;
  const float dOc = vOP.z - vOM.z, dOd = vOP.w - vOM.w;

  // Inward y-neighbor via half-wave exchange (partner row is never clamped).
  const float iCa = __shfl_xor(vC.x, 32), iCb = __shfl_xor(vC.y, 32);
  const float iCc = __shfl_xor(vC.z, 32), iCd = __shfl_xor(vC.w, 32);
  const float iDa = __shfl_xor(dxa, 32),  iDb = __shfl_xor(dxb, 32);
  const float iDc = __shfl_xor(dxc, 32),  iDd = __shfl_xor(dxd, 32);

  // y combines — sign-free (sgn^2=1 in dij*djk; dj enters only as dj^2/sy).
  const float sya = iCa + vOY.x, syb = iCb + vOY.y;
  const float syc = iCc + vOY.z, syd = iCd + vOY.w;
  const float dya = vOY.x - iCa, dyb = vOY.y - iCb;
  const float dyc = vOY.z - iCc, dyd = vOY.w - iCd;
  const float ja  = dOa - iDa,   jb  = dOb - iDb;
  const float jc  = dOc - iDc,   jd  = dOd - iDd;

  // z-halo from adjacent lanes (lane i-1 holds z0-4..z0-1). Clamp lanes
  // (tid&31)==0 / ==31 are select-overridden, so the +-1 shuffles never leak
  // across the 32-lane z-line boundary (where y changes).
  const bool zlo = (z0 == 0), zhi = (z0 == 124);
  float clo  = __shfl_up  (vC.w, 1);  clo  = zlo ? vC.x : clo;
  float chi  = __shfl_down(vC.x, 1);  chi  = zhi ? vC.w : chi;
  float dxm1 = __shfl_up  (dxd, 1);   dxm1 = zlo ? dxa : dxm1;
  float dxp4 = __shfl_down(dxa, 1);   dxp4 = zhi ? dxd : dxp4;
  float dym1 = __shfl_up  (dyd, 1);   dym1 = zlo ? dya : dym1;
  float dyp4 = __shfl_down(dya, 1);   dyp4 = zhi ? dyd : dyp4;

  float s12 = 0.f, s3 = 0.f;
  elem(clo,  vC.x, vC.y, dxa, sxa, dya, sya, dxb - dxm1, dyb - dym1, ja, t4.x, s12, s3);
  elem(vC.x, vC.y, vC.z, dxb, sxb, dyb, syb, dxc - dxa,  dyc - dya,  jb, t4.y, s12, s3);
  elem(vC.y, vC.z, vC.w, dxc, sxc, dyc, syc, dxd - dxb,  dyd - dyb,  jc, t4.z, s12, s3);
  elem(vC.z, vC.w, chi,  dxd, sxd, dyd, syd, dxp4 - dxc, dyp4 - dyc, jd, t4.w, s12, s3);

  // Single scalar per thread (MIU=1, abs no-ops) -> 1-value reduce, 1 partial.
  float v = s12 + s3;
  wave_reduce1(v);
  __shared__ float l[8];
  const int lane = tid & 63, wv = tid >> 6;
  if (lane == 0) l[wv] = v;
  __syncthreads();
  if (tid == 0) {
    float p = 0.f;
#pragma unroll
    for (int w = 0; w < 8; ++w) p += l[w];
    partials[blockIdx.x] = p;
  }
}

__global__ __launch_bounds__(1024) void ace_final(
    const float* __restrict__ partials, float* __restrict__ out) {
  const int tid = threadIdx.x;
  float s = 0.f;
  const float4* p4 = (const float4*)partials;   // 6144 floats = 1536 float4
#pragma unroll
  for (int i = tid; i < NBLK / 4; i += 1024) {
    const float4 a = p4[i];
    s += (a.x + a.y) + (a.z + a.w);
  }
  wave_reduce1(s);
  __shared__ float l[16];
  const int lane = tid & 63, wv = tid >> 6;
  if (lane == 0) l[wv] = s;
  __syncthreads();
  if (tid == 0) {
    float S = 0.f;
#pragma unroll
    for (int w = 0; w < 16; ++w) S += l[w];
    out[0] = S + ALPHA_ * (float)NTOT;
  }
}

extern "C" void kernel_launch(void* const* d_in, const int* in_sizes, int n_in,
                              void* d_out, int out_size, void* d_ws, size_t ws_size,
                              hipStream_t stream) {
  const float* pred  = (const float*)d_in[0];   // y_pred
  const float* truth = (const float*)d_in[1];   // y_true
  float* out      = (float*)d_out;
  float* partials = (float*)d_ws;               // NBLK floats = 24.6 KB

  ace_main<<<NBLK, 512, 0, stream>>>(pred, truth, partials);
  ace_final<<<1, 1024, 0, stream>>>(partials, out);
}